// Round 6
// baseline (258.499 us; speedup 1.0000x reference)
//
#include <hip/hip_runtime.h>
#include <cstdint>
#include <cstddef>

// ---- problem constants ----
#define NBATCH   16384
#define NSEC     9
#define NOC      50        // conv output channels per section
#define NOCP     64        // padded to 4 MFMA n-tiles
#define KPAD     256       // padded K for 8 x 32 MFMA steps
#define KREAL    240
#define XROW     1640      // 41*40 floats per batch
#define XSF      1664      // f16 elems per LDS row = 208 units * 8
#define TB       16        // batches per block
#define OUTHALF  7372800   // 16384*50*9
#define THRESH   6.2f

typedef _Float16 half8  __attribute__((ext_vector_type(8)));
typedef float    f32x4  __attribute__((ext_vector_type(4)));

__device__ inline half8 cvt8(float4 a, float4 b) {
    half8 h;
    h[0] = (_Float16)a.x; h[1] = (_Float16)a.y;
    h[2] = (_Float16)a.z; h[3] = (_Float16)a.w;
    h[4] = (_Float16)b.x; h[5] = (_Float16)b.y;
    h[6] = (_Float16)b.z; h[7] = (_Float16)b.w;
    return h;
}

__device__ inline void stg_load(const float* __restrict__ xrow, int u,
                                float4& a, float4& b) {
    if (u < 205) {           // 205*8 == 1640 exactly
        a = *(const float4*)(xrow + u * 8);
        b = *(const float4*)(xrow + u * 8 + 4);
    } else {
        a = float4{0, 0, 0, 0};
        b = float4{0, 0, 0, 0};
    }
}

__device__ inline void stg_write(_Float16* lrow, int u, int ssw,
                                 float4 a, float4 b) {
    *(half8*)(lrow + ((u ^ ssw) << 3)) = cvt8(a, b);
}

// ---- k0: W fp32 [9][50][240] -> f16 [9][64][256], zero padded ----
__global__ __launch_bounds__(256)
void wconv_kernel(const float* __restrict__ W, _Float16* __restrict__ wks) {
    int idx = blockIdx.x * 256 + threadIdx.x;        // 0 .. 147455
    int k   = idx & 255;
    int ocp = (idx >> 8) & 63;
    int sec = idx >> 14;
    float v = 0.0f;
    if (ocp < NOC && k < KREAL)
        v = W[(size_t)(sec * NOC + ocp) * KREAL + k];
    wks[idx] = (_Float16)v;
}

// ---- fused kernel: h-in-M 2Mx2N core, per-section direct global writes ----
// M-row m = 4*b_local + h.  wave w: batches 8*(w>>1)..+7 (2 m-tiles),
// oc 32*(w&1)..+31 (2 n-tiles).  Each A frag feeds 2 MFMAs, each B frag 2.
// Pool over h = intra-lane max over the 4 acc regs (D row = quad*4+j ->
// batch=quad, h=j).  Results stored straight to global per section:
// no res[9][2][2] array, no LDS transpose epilogue -> live state fits the
// 170-reg/wave budget of waves_per_eu=3 (12 waves/CU) without spilling.
__global__ __launch_bounds__(256, 3)
void fused_kernel(const float* __restrict__ x,
                  const _Float16* __restrict__ wks,
                  float* __restrict__ out) {
    __shared__ __align__(16) _Float16 xs[TB * XSF];   // 53248 B; 3 blocks/CU

    const int tid = threadIdx.x;
    const size_t b0 = (size_t)blockIdx.x * TB;

    // staging geometry: thread t owns row b=t>>4, units u=(t&15)+16j
    // element k of row b lives at unit ((k>>3) ^ (b&7)) (16B runs preserved)
    const int bb  = tid >> 4;
    const int u16 = tid & 15;
    const int ssw = bb & 7;
    const float* xrow = x + (b0 + bb) * XROW;
    _Float16* lrow = xs + bb * XSF;

    // compute-side lane constants
    const int lane  = tid & 63;
    const int w     = tid >> 6;
    const int l15   = lane & 15;
    const int quad  = lane >> 4;
    const int mbase = 8 * (w >> 1);          // batch-local base of this wave
    const int nbase = 32 * (w & 1);          // oc base of this wave

    // A rows for the two m-tiles: batch = mbase + 4*mt + (l15>>2), h = l15&3
    const int row0 = mbase + (l15 >> 2);
    const int row1 = row0 + 4;
    const _Float16* arow0 = xs + row0 * XSF;
    const _Float16* arow1 = xs + row1 * XSF;
    const int sw0 = row0 & 7;
    const int sw1 = row1 & 7;
    const int ubase = (l15 & 3) * 5 + quad;  // unit = s*20 + (h4+kk)*4 + ubase

    // B: lane covers oc = nbase + nt*16 + l15, elems quad*8..+7, k chunk kk*32
    const _Float16* wb = wks + (size_t)(nbase + l15) * KPAD + quad * 8;

    // output base for this lane: batch = b0+mbase+quad (+4 for mt1),
    // oc = nbase+l15 (+16 for nt1); out[b*450 + oc*9 + s]
    float* po = out + ((size_t)(b0 + mbase + quad)) * 450 + (nbase + l15) * 9;
    const bool v1 = (nbase + 16 + l15) < NOC;   // nt1 mask (nt0 always valid)

    half8 bv0[2][4], bv1[2][4];              // two half-section B buffers
    f32x4 acc00, acc01, acc10, acc11;

#define BPREF(ss, hh, B) { \
    const _Float16* wsec_ = wb + (size_t)((ss) * NOCP) * KPAD + (hh) * 128; \
    B[0][0] = *(const half8*)(wsec_);                \
    B[0][1] = *(const half8*)(wsec_ + 32);           \
    B[0][2] = *(const half8*)(wsec_ + 64);           \
    B[0][3] = *(const half8*)(wsec_ + 96);           \
    B[1][0] = *(const half8*)(wsec_ + 16 * KPAD);        \
    B[1][1] = *(const half8*)(wsec_ + 16 * KPAD + 32);   \
    B[1][2] = *(const half8*)(wsec_ + 16 * KPAD + 64);   \
    B[1][3] = *(const half8*)(wsec_ + 16 * KPAD + 96);   \
}

#define CHALF(ss, hh, B) { \
    _Pragma("unroll") \
    for (int kk = 0; kk < 4; ++kk) { \
        const int unit_ = (ss) * 20 + ((hh) * 4 + kk) * 4 + ubase; \
        half8 av0_ = *(const half8*)(arow0 + ((unit_ ^ sw0) << 3)); \
        half8 av1_ = *(const half8*)(arow1 + ((unit_ ^ sw1) << 3)); \
        acc00 = __builtin_amdgcn_mfma_f32_16x16x32_f16(av0_, B[0][kk], acc00, 0, 0, 0); \
        acc01 = __builtin_amdgcn_mfma_f32_16x16x32_f16(av0_, B[1][kk], acc01, 0, 0, 0); \
        acc10 = __builtin_amdgcn_mfma_f32_16x16x32_f16(av1_, B[0][kk], acc10, 0, 0, 0); \
        acc11 = __builtin_amdgcn_mfma_f32_16x16x32_f16(av1_, B[1][kk], acc11, 0, 0, 0); \
    } \
}

#define SECTION(ss) { \
    BPREF(ss, 1, bv1); \
    acc00 = f32x4{}; acc01 = f32x4{}; acc10 = f32x4{}; acc11 = f32x4{}; \
    CHALF(ss, 0, bv0); \
    if ((ss) < 8) BPREF((ss) + 1, 0, bv0); \
    CHALF(ss, 1, bv1); \
    { \
        float r00 = fmaxf(fmaxf(acc00[0], acc00[1]), fmaxf(acc00[2], acc00[3])); \
        float r01 = fmaxf(fmaxf(acc01[0], acc01[1]), fmaxf(acc01[2], acc01[3])); \
        float r10 = fmaxf(fmaxf(acc10[0], acc10[1]), fmaxf(acc10[2], acc10[3])); \
        float r11 = fmaxf(fmaxf(acc11[0], acc11[1]), fmaxf(acc11[2], acc11[3])); \
        po[ss]        = r00; \
        po[OUTHALF + ss]        = (r00 > THRESH) ? 1.0f : 0.0f; \
        po[1800 + ss] = r10;    /* mt1: batch+4 -> +4*450 */ \
        po[OUTHALF + 1800 + ss] = (r10 > THRESH) ? 1.0f : 0.0f; \
        if (v1) { \
            po[144 + ss]  = r01;    /* nt1: oc+16 -> +144 */ \
            po[OUTHALF + 144 + ss]  = (r01 > THRESH) ? 1.0f : 0.0f; \
            po[1944 + ss] = r11; \
            po[OUTHALF + 1944 + ss] = (r11 > THRESH) ? 1.0f : 0.0f; \
        } \
    } \
}

    // ---- staging: all 205 units upfront (no cross-section staging regs) ----
    {
        #pragma unroll
        for (int c = 0; c < 2; ++c) {
            const int jn = c ? 6 : 7;
            float4 va[7], vb[7];
            #pragma unroll
            for (int jj = 0; jj < 7; ++jj)
                if (jj < jn)
                    stg_load(xrow, u16 + 16 * (c * 7 + jj), va[jj], vb[jj]);
            if (c == 0) BPREF(0, 0, bv0);    // B s0/h0 under staging latency
            #pragma unroll
            for (int jj = 0; jj < 7; ++jj)
                if (jj < jn)
                    stg_write(lrow, u16 + 16 * (c * 7 + jj), ssw, va[jj], vb[jj]);
        }
    }
    __syncthreads();                         // whole x tile ready

    SECTION(0);
    SECTION(1);
    SECTION(2);
    SECTION(3);
    SECTION(4);
    SECTION(5);
    SECTION(6);
    SECTION(7);
    SECTION(8);
}

// ---- fallback (only if ws too small): direct fp32, correct but slow ----
__global__ __launch_bounds__(256)
void naive_kernel(const float* __restrict__ x, const float* __restrict__ W,
                  float* __restrict__ out) {
    size_t idx = (size_t)blockIdx.x * 256 + threadIdx.x;
    if (idx >= OUTHALF) return;
    int s  = (int)(idx % NSEC);
    int oc = (int)((idx / NSEC) % NOC);
    int b  = (int)(idx / (NSEC * NOC));
    const float* xb = x + (size_t)b * XROW + s * 160;
    const float* wv = W + (size_t)(s * NOC + oc) * KREAL;
    float best = -1e30f;
    for (int h0 = 0; h0 < 4; ++h0) {
        float acc = 0.0f;
        for (int k = 0; k < KREAL; ++k)
            acc += xb[h0 * 40 + k] * wv[k];
        best = fmaxf(best, acc);
    }
    out[idx] = best;
    out[OUTHALF + idx] = (best > THRESH) ? 1.0f : 0.0f;
}

extern "C" void kernel_launch(void* const* d_in, const int* in_sizes, int n_in,
                              void* d_out, int out_size, void* d_ws, size_t ws_size,
                              hipStream_t stream) {
    const float* x = (const float*)d_in[0];   // [16384,1,41,40]
    const float* W = (const float*)d_in[1];   // [9,50,1,6,40]
    float* out = (float*)d_out;               // pots(7372800) ++ spks(7372800)

    const size_t w_bytes = (size_t)NSEC * NOCP * KPAD * sizeof(_Float16); // 294912

    if (ws_size < w_bytes) {
        naive_kernel<<<(OUTHALF + 255) / 256, 256, 0, stream>>>(x, W, out);
        return;
    }

    _Float16* wks = (_Float16*)d_ws;

    wconv_kernel<<<(NSEC * NOCP * KPAD) / 256, 256, 0, stream>>>(W, wks);
    fused_kernel<<<NBATCH / TB, 256, 0, stream>>>(x, wks, out);
}

// Round 8
// 223.308 us; speedup vs baseline: 1.1576x; 1.1576x over previous
//
#include <hip/hip_runtime.h>
#include <cstdint>
#include <cstddef>

// ---- problem constants ----
#define NBATCH   16384
#define NSEC     9
#define NOC      50        // conv output channels per section
#define NOCP     64        // padded to 4 MFMA n-tiles
#define KPAD     256       // padded K for 8 x 32 MFMA steps
#define KREAL    240
#define XROW     1640      // 41*40 floats per batch
#define XSF      1664      // f16 elems per LDS row = 208 units * 8
#define TB       8         // batches per block (occupancy > reuse)
#define OUTHALF  7372800   // 16384*50*9
#define THRESH   6.2f

typedef _Float16 half8  __attribute__((ext_vector_type(8)));
typedef float    f32x4  __attribute__((ext_vector_type(4)));

__device__ inline half8 cvt8(float4 a, float4 b) {
    half8 h;
    h[0] = (_Float16)a.x; h[1] = (_Float16)a.y;
    h[2] = (_Float16)a.z; h[3] = (_Float16)a.w;
    h[4] = (_Float16)b.x; h[5] = (_Float16)b.y;
    h[6] = (_Float16)b.z; h[7] = (_Float16)b.w;
    return h;
}

__device__ inline void stg_load(const float* __restrict__ xrow, int u,
                                float4& a, float4& b) {
    if (u < 205) {           // 205*8 == 1640 exactly
        a = *(const float4*)(xrow + u * 8);
        b = *(const float4*)(xrow + u * 8 + 4);
    } else {
        a = float4{0, 0, 0, 0};
        b = float4{0, 0, 0, 0};
    }
}

__device__ inline void stg_write(_Float16* lrow, int u, int ssw,
                                 float4 a, float4 b) {
    *(half8*)(lrow + ((u ^ ssw) << 3)) = cvt8(a, b);
}

// ---- k0: W fp32 [9][50][240] -> f16 [9][64][256], zero padded ----
__global__ __launch_bounds__(256)
void wconv_kernel(const float* __restrict__ W, _Float16* __restrict__ wks) {
    int idx = blockIdx.x * 256 + threadIdx.x;        // 0 .. 147455
    int k   = idx & 255;
    int ocp = (idx >> 8) & 63;
    int sec = idx >> 14;
    float v = 0.0f;
    if (ocp < NOC && k < KREAL)
        v = W[(size_t)(sec * NOC + ocp) * KREAL + k];
    wks[idx] = (_Float16)v;
}

// ---- fused kernel: TB=8, h-in-M, wave = 2 m-tiles x 1 n-tile ----
// M-row m = 4*b_local + h -> 8 batches = 2 M-tiles of 16 rows.
// wave w owns oc tile w (16 oc) and BOTH m-tiles (minimal B traffic: block
// reads W exactly once).  Pool over h = intra-lane max over 4 acc regs
// (D row = quad*4+j -> batch = quad, h = j).
// LDS 26624 B -> 4 blocks/CU at launch_bounds(256,4): 16 waves/CU (50% occ),
// 128 unified regs/wave.
// R7 bug fixed: with 32 threads/row, tranche j=6 spans u=192..223 but a row
// has only 208 units -- u>=208 wrote zeros into the NEXT row (race, wrong
// results).  Only threads with u32<16 do j=6 (u=192..207, zeros for 205+).
__global__ __launch_bounds__(256, 4)
void fused_kernel(const float* __restrict__ x,
                  const _Float16* __restrict__ wks,
                  float* __restrict__ out) {
    __shared__ __align__(16) _Float16 xs[TB * XSF];   // 26624 B

    const int tid = threadIdx.x;
    const size_t b0 = (size_t)blockIdx.x * TB;

    // staging geometry: thread t owns row b=t>>5 (32 threads/row),
    // units u = (t&31)+32j.  element k of row b lives at unit
    // ((k>>3) ^ (b&7)) (16B runs preserved).
    const int bb  = tid >> 5;
    const int u32 = tid & 31;
    const int ssw = bb & 7;
    const float* xrow = x + (b0 + bb) * XROW;
    _Float16* lrow = xs + bb * XSF;

    // compute-side lane constants
    const int lane  = tid & 63;
    const int w     = tid >> 6;      // wave = oc tile (16 oc each)
    const int l15   = lane & 15;
    const int quad  = lane >> 4;

    // A rows for the two m-tiles: batch = 4*mt + (l15>>2), h = l15&3
    const int row0 = l15 >> 2;               // 0..3
    const int row1 = row0 + 4;               // 4..7
    const _Float16* arow0 = xs + row0 * XSF;
    const _Float16* arow1 = xs + row1 * XSF;
    const int sw0 = row0 & 7;
    const int sw1 = row1 & 7;
    const int ubase = (l15 & 3) * 5 + quad;  // unit = s*20 + (h4+kk)*4 + ubase

    // B: lane covers oc = w*16 + l15, elems quad*8..+7, k chunk kk*32
    const _Float16* wb = wks + (size_t)(w * 16 + l15) * KPAD + quad * 8;
    const int oc = w * 16 + l15;

    half8 bv0[4], bv1[4];                    // two half-section B buffers
    f32x4 acc0, acc1;
    float res[NSEC][2];

#define BPREF(ss, hh, B) { \
    const _Float16* wsec_ = wb + (size_t)((ss) * NOCP) * KPAD + (hh) * 128; \
    B[0] = *(const half8*)(wsec_);        \
    B[1] = *(const half8*)(wsec_ + 32);   \
    B[2] = *(const half8*)(wsec_ + 64);   \
    B[3] = *(const half8*)(wsec_ + 96);   \
}

#define CHALF(ss, hh, B) { \
    _Pragma("unroll") \
    for (int kk = 0; kk < 4; ++kk) { \
        const int unit_ = (ss) * 20 + ((hh) * 4 + kk) * 4 + ubase; \
        half8 av0_ = *(const half8*)(arow0 + ((unit_ ^ sw0) << 3)); \
        half8 av1_ = *(const half8*)(arow1 + ((unit_ ^ sw1) << 3)); \
        acc0 = __builtin_amdgcn_mfma_f32_16x16x32_f16(av0_, B[kk], acc0, 0, 0, 0); \
        acc1 = __builtin_amdgcn_mfma_f32_16x16x32_f16(av1_, B[kk], acc1, 0, 0, 0); \
    } \
}

#define SECTION(ss) { \
    BPREF(ss, 1, bv1); \
    acc0 = f32x4{}; acc1 = f32x4{}; \
    CHALF(ss, 0, bv0); \
    if ((ss) < 8) BPREF((ss) + 1, 0, bv0); \
    CHALF(ss, 1, bv1); \
    res[ss][0] = fmaxf(fmaxf(acc0[0], acc0[1]), fmaxf(acc0[2], acc0[3])); \
    res[ss][1] = fmaxf(fmaxf(acc1[0], acc1[1]), fmaxf(acc1[2], acc1[3])); \
}

    // ---- staging: tranches j=0..3 (u<=127), j=4..5 (u<=191),
    //      j=6 only for u32<16 (u=192..207; zeros for 205..207) ----
    {
        float4 va[4], vb[4];
        #pragma unroll
        for (int j = 0; j < 4; ++j)          // u <= 127, no guard
            stg_load(xrow, u32 + 32 * j, va[j], vb[j]);
        BPREF(0, 0, bv0);                    // B s0/h0 under staging latency
        #pragma unroll
        for (int j = 0; j < 4; ++j)
            stg_write(lrow, u32 + 32 * j, ssw, va[j], vb[j]);
        #pragma unroll
        for (int j = 4; j < 6; ++j)          // u <= 191, no guard
            stg_load(xrow, u32 + 32 * j, va[j - 4], vb[j - 4]);
        if (u32 < 16)                        // u = 192..207 only
            stg_load(xrow, u32 + 192, va[2], vb[2]);
        #pragma unroll
        for (int j = 4; j < 6; ++j)
            stg_write(lrow, u32 + 32 * j, ssw, va[j - 4], vb[j - 4]);
        if (u32 < 16)
            stg_write(lrow, u32 + 192, ssw, va[2], vb[2]);
    }
    __syncthreads();                         // whole x tile ready

    SECTION(0);
    SECTION(1);
    SECTION(2);
    SECTION(3);
    SECTION(4);
    SECTION(5);
    SECTION(6);
    SECTION(7);
    SECTION(8);

    // ---- reuse xs as fp32 transpose buffer t[8][450] (14400 B) ----
    __syncthreads();
    float* tb = (float*)xs;
    if (oc < NOC) {
        #pragma unroll
        for (int mt = 0; mt < 2; ++mt) {
            const int bl = mt * 4 + quad;
            #pragma unroll
            for (int s = 0; s < NSEC; ++s)
                tb[bl * 450 + oc * 9 + s] = res[s][mt];
        }
    }
    __syncthreads();

    // coalesced float4 final write: pots then spikes (900 float4)
    const size_t ob = b0 * 450;
    const float4* t4 = (const float4*)tb;
    float4* o4  = (float4*)(out + ob);
    float4* o4s = (float4*)(out + OUTHALF + ob);
    for (int i = tid; i < TB * 450 / 4; i += 256) {
        float4 v = t4[i];
        o4[i] = v;
        float4 sp;
        sp.x = (v.x > THRESH) ? 1.0f : 0.0f;
        sp.y = (v.y > THRESH) ? 1.0f : 0.0f;
        sp.z = (v.z > THRESH) ? 1.0f : 0.0f;
        sp.w = (v.w > THRESH) ? 1.0f : 0.0f;
        o4s[i] = sp;
    }
}

// ---- fallback (only if ws too small): direct fp32, correct but slow ----
__global__ __launch_bounds__(256)
void naive_kernel(const float* __restrict__ x, const float* __restrict__ W,
                  float* __restrict__ out) {
    size_t idx = (size_t)blockIdx.x * 256 + threadIdx.x;
    if (idx >= OUTHALF) return;
    int s  = (int)(idx % NSEC);
    int oc = (int)((idx / NSEC) % NOC);
    int b  = (int)(idx / (NSEC * NOC));
    const float* xb = x + (size_t)b * XROW + s * 160;
    const float* wv = W + (size_t)(s * NOC + oc) * KREAL;
    float best = -1e30f;
    for (int h0 = 0; h0 < 4; ++h0) {
        float acc = 0.0f;
        for (int k = 0; k < KREAL; ++k)
            acc += xb[h0 * 40 + k] * wv[k];
        best = fmaxf(best, acc);
    }
    out[idx] = best;
    out[OUTHALF + idx] = (best > THRESH) ? 1.0f : 0.0f;
}

extern "C" void kernel_launch(void* const* d_in, const int* in_sizes, int n_in,
                              void* d_out, int out_size, void* d_ws, size_t ws_size,
                              hipStream_t stream) {
    const float* x = (const float*)d_in[0];   // [16384,1,41,40]
    const float* W = (const float*)d_in[1];   // [9,50,1,6,40]
    float* out = (float*)d_out;               // pots(7372800) ++ spks(7372800)

    const size_t w_bytes = (size_t)NSEC * NOCP * KPAD * sizeof(_Float16); // 294912

    if (ws_size < w_bytes) {
        naive_kernel<<<(OUTHALF + 255) / 256, 256, 0, stream>>>(x, W, out);
        return;
    }

    _Float16* wks = (_Float16*)d_ws;

    wconv_kernel<<<(NSEC * NOCP * KPAD) / 256, 256, 0, stream>>>(W, wks);
    fused_kernel<<<NBATCH / TB, 256, 0, stream>>>(x, wks, out);
}